// Round 7
// baseline (835.625 us; speedup 1.0000x reference)
//
#include <hip/hip_runtime.h>

#define Nn 4096
#define Cc 256
#define NN2 ((size_t)Nn * Nn)

typedef __attribute__((ext_vector_type(8))) short bf16x8;
typedef __attribute__((ext_vector_type(4))) float f32x4;

__device__ __forceinline__ unsigned short f2bf(float f) {
    union { float f; unsigned u; } v; v.f = f;
    unsigned r = v.u + 0x7FFF + ((v.u >> 16) & 1);
    return (unsigned short)(r >> 16);
}

__device__ __forceinline__ bf16x8 pack2(const float4& a, const float4& b) {
    bf16x8 o;
    o[0] = (short)f2bf(a.x); o[1] = (short)f2bf(a.y);
    o[2] = (short)f2bf(a.z); o[3] = (short)f2bf(a.w);
    o[4] = (short)f2bf(b.x); o[5] = (short)f2bf(b.y);
    o[6] = (short)f2bf(b.z); o[7] = (short)f2bf(b.w);
    return o;
}

// exp 8 floats (two float4), accumulate sum into sacc, return packed bf16x8
__device__ __forceinline__ bf16x8 exp8acc(const float4 a, const float4 b, float& sacc) {
    const float s0 = __expf(a.x), s1 = __expf(a.y), s2 = __expf(a.z), s3 = __expf(a.w);
    const float s4 = __expf(b.x), s5 = __expf(b.y), s6 = __expf(b.z), s7 = __expf(b.w);
    sacc += ((s0 + s1) + (s2 + s3)) + ((s4 + s5) + (s6 + s7));
    bf16x8 o;
    o[0] = (short)f2bf(s0); o[1] = (short)f2bf(s1);
    o[2] = (short)f2bf(s2); o[3] = (short)f2bf(s3);
    o[4] = (short)f2bf(s4); o[5] = (short)f2bf(s5);
    o[6] = (short)f2bf(s6); o[7] = (short)f2bf(s7);
    return o;
}

// ---------------------------------------------------------------------------
// Kernel 1 v2: V[b,o,n] = bf16( sum_c W[o,c]*X[b,c,n] + bias[o] )
// Restructured for latency hiding: 1024 blocks (4b x 128 ntile x 2 chalf),
// 256 thr / 4 waves, each block computes [128 c x 32 n]. 4 blocks/CU =
// 16 waves/CU (vs 8 before); per-k0 W-load count halved per wave.
// X staged via LDS (stride-33). X read x2 redundancy (chalf) = +16.8 MB, ok.
// ---------------------------------------------------------------------------
__global__ __launch_bounds__(256) void value_gemm(
    const float* __restrict__ X, const float* __restrict__ W,
    const float* __restrict__ bias, unsigned short* __restrict__ Vout)
{
    __shared__ float Xs[256][33];

    const int t = threadIdx.x;
    const int blk = blockIdx.x;
    const int b  = blk >> 8;
    const int n0 = ((blk >> 1) & 127) << 5;
    const int ch = (blk & 1) << 7;           // c-half offset 0/128
    const int wave = t >> 6, lane = t & 63;
    const int lrow = lane & 15, lq = lane >> 4;

    const float* Xb = X + (size_t)b * Cc * Nn + n0;

    {
        const int r0 = t >> 3, c4 = (t & 7) << 2;
        #pragma unroll
        for (int i = 0; i < 8; ++i) {
            const int r = r0 + i * 32;
            const float4 v = *(const float4*)(Xb + (size_t)r * Nn + c4);
            Xs[r][c4 + 0] = v.x; Xs[r][c4 + 1] = v.y;
            Xs[r][c4 + 2] = v.z; Xs[r][c4 + 3] = v.w;
        }
    }
    __syncthreads();

    f32x4 acc[2][2] = {};   // [ci][mi]

    #pragma unroll 2
    for (int k0 = 0; k0 < Cc; k0 += 32) {
        bf16x8 af[2];
        #pragma unroll
        for (int ci = 0; ci < 2; ++ci) {
            const float* wp = W + (size_t)(ch + wave * 32 + ci * 16 + lrow) * Cc + k0 + lq * 8;
            af[ci] = pack2(*(const float4*)wp, *(const float4*)(wp + 4));
        }
        bf16x8 bp[2];
        #pragma unroll
        for (int mi = 0; mi < 2; ++mi) {
            const int n = mi * 16 + lrow;
            bf16x8 o;
            #pragma unroll
            for (int j = 0; j < 8; ++j) o[j] = (short)f2bf(Xs[k0 + lq * 8 + j][n]);
            bp[mi] = o;
        }
        #pragma unroll
        for (int ci = 0; ci < 2; ++ci)
            #pragma unroll
            for (int mi = 0; mi < 2; ++mi)
                acc[ci][mi] = __builtin_amdgcn_mfma_f32_16x16x32_bf16(
                    af[ci], bp[mi], acc[ci][mi], 0, 0, 0);
    }

    #pragma unroll
    for (int ci = 0; ci < 2; ++ci) {
        #pragma unroll
        for (int rr = 0; rr < 4; ++rr) {
            const int o = ch + wave * 32 + ci * 16 + lq * 4 + rr;
            const float bo = bias[o];
            #pragma unroll
            for (int mi = 0; mi < 2; ++mi) {
                const int n = n0 + mi * 16 + lrow;
                Vout[((size_t)(b * Cc + o)) * Nn + n] = f2bf(acc[ci][mi][rr] + bo);
            }
        }
    }
}

// ---------------------------------------------------------------------------
// Kernel 2 v7: BARRIER-FREE, LDS-FREE — with regalloc finally PINNED.
// v6 failed because __launch_bounds__(512,2) only sets MIN waves/EU; the
// compiler chose 4 waves/EU (128-VGPR cap) and spilled 59 MB of scratch.
// amdgpu_waves_per_eu(2,2) pins min AND max -> 256-VGPR budget -> the
// ~190-reg E/V ping-pong fits, prefetch survives, zero spill.
// (Check: VGPR >= 180, WRITE_SIZE ~16.4 MB.)
// Block 512 = 8 free-running waves = 4 c-slices(64) x 2 m-halves(32) of one
// (b, 64-row m-tile). E shared across c-slice waves via L1/L2 (v6 FETCH
// proved dedup works: 290 MB, not 4x268). Grid 256 = 1 block/CU.
// ---------------------------------------------------------------------------
__global__ __launch_bounds__(512)
__attribute__((amdgpu_waves_per_eu(2, 2)))
void attn_gemm(
    const unsigned short* __restrict__ V, const float* __restrict__ E,
    const float* __restrict__ X, const float* __restrict__ gamma,
    float* __restrict__ Out)
{
    const int t = threadIdx.x;
    const int wave = t >> 6, lane = t & 63;
    const int lrow = lane & 15, lq = lane >> 4;
    const int blk = blockIdx.x;
    const int b  = blk & 3;
    const int m0 = (blk >> 2) << 6;     // 64-row m-tile
    const int c0 = (wave & 3) << 6;     // c-slice
    const int mh = (wave >> 2) << 5;    // m-half (0 or 32)

    // E row pointers for this lane's two m-rows (mi=0: mh+lrow, mi=1: mh+16+lrow)
    const float* ep0 = E + (size_t)b * NN2 + (size_t)(m0 + mh + lrow) * Nn + lq * 8;
    const float* ep1 = ep0 + (size_t)16 * Nn;

    // V fragments: rows c0+ci*16+lrow, cols lq*8 (+ k*64 + kk*32)
    const unsigned short* vbase = V + (size_t)(b * Cc + c0) * Nn;
    int voff[4];
    #pragma unroll
    for (int ci = 0; ci < 4; ++ci) voff[ci] = (ci * 16 + lrow) * Nn + lq * 8;

    f32x4 acc[4][2] = {};            // [ci][mi]
    float sacc0 = 0.f, sacc1 = 0.f;  // exp sums for rows mh+lrow / mh+16+lrow

    // E regs: [mi*4 + kk*2 + h]; V regs: [kk*4 + ci]. Ping-pong A/B.
    float4 eA[8], eB[8];
    bf16x8 vA[8], vB[8];

    // ---- prologue: k=0 -> A, k=1 -> B ----
    #pragma unroll
    for (int kk = 0; kk < 2; ++kk) {
        eA[0 + kk * 2 + 0] = *(const float4*)(ep0 + kk * 32);
        eA[0 + kk * 2 + 1] = *(const float4*)(ep0 + kk * 32 + 4);
        eA[4 + kk * 2 + 0] = *(const float4*)(ep1 + kk * 32);
        eA[4 + kk * 2 + 1] = *(const float4*)(ep1 + kk * 32 + 4);
        eB[0 + kk * 2 + 0] = *(const float4*)(ep0 + 64 + kk * 32);
        eB[0 + kk * 2 + 1] = *(const float4*)(ep0 + 64 + kk * 32 + 4);
        eB[4 + kk * 2 + 0] = *(const float4*)(ep1 + 64 + kk * 32);
        eB[4 + kk * 2 + 1] = *(const float4*)(ep1 + 64 + kk * 32 + 4);
    }
    #pragma unroll
    for (int kk = 0; kk < 2; ++kk)
        #pragma unroll
        for (int ci = 0; ci < 4; ++ci) {
            vA[kk * 4 + ci] = *(const bf16x8*)(vbase + voff[ci] + kk * 32);
            vB[kk * 4 + ci] = *(const bf16x8*)(vbase + voff[ci] + 64 + kk * 32);
        }

    // half-step: consume E/V set for step ks, refill same set for ks+2.
#define HALF(Ee, Vv, ks)                                                      \
    {                                                                          \
        bf16x8 bfr00 = exp8acc(Ee[0], Ee[1], sacc0);  /* mi0 kk0 */            \
        bf16x8 bfr01 = exp8acc(Ee[2], Ee[3], sacc0);  /* mi0 kk1 */            \
        bf16x8 bfr10 = exp8acc(Ee[4], Ee[5], sacc1);  /* mi1 kk0 */            \
        bf16x8 bfr11 = exp8acc(Ee[6], Ee[7], sacc1);  /* mi1 kk1 */            \
        const int kc = (((ks) + 2) & 63) << 6;                                 \
        Ee[0] = *(const float4*)(ep0 + kc);                                    \
        Ee[1] = *(const float4*)(ep0 + kc + 4);                                \
        Ee[2] = *(const float4*)(ep0 + kc + 32);                               \
        Ee[3] = *(const float4*)(ep0 + kc + 36);                               \
        Ee[4] = *(const float4*)(ep1 + kc);                                    \
        Ee[5] = *(const float4*)(ep1 + kc + 4);                                \
        Ee[6] = *(const float4*)(ep1 + kc + 32);                               \
        Ee[7] = *(const float4*)(ep1 + kc + 36);                               \
        _Pragma("unroll")                                                      \
        for (int ci = 0; ci < 4; ++ci) {                                       \
            acc[ci][0] = __builtin_amdgcn_mfma_f32_16x16x32_bf16(              \
                Vv[ci], bfr00, acc[ci][0], 0, 0, 0);                           \
            acc[ci][1] = __builtin_amdgcn_mfma_f32_16x16x32_bf16(              \
                Vv[ci], bfr10, acc[ci][1], 0, 0, 0);                           \
        }                                                                      \
        _Pragma("unroll")                                                      \
        for (int ci = 0; ci < 4; ++ci) {                                       \
            acc[ci][0] = __builtin_amdgcn_mfma_f32_16x16x32_bf16(              \
                Vv[4 + ci], bfr01, acc[ci][0], 0, 0, 0);                       \
            acc[ci][1] = __builtin_amdgcn_mfma_f32_16x16x32_bf16(              \
                Vv[4 + ci], bfr11, acc[ci][1], 0, 0, 0);                       \
        }                                                                      \
        _Pragma("unroll")                                                      \
        for (int ci = 0; ci < 4; ++ci) {                                       \
            Vv[ci]     = *(const bf16x8*)(vbase + voff[ci] + kc);              \
            Vv[4 + ci] = *(const bf16x8*)(vbase + voff[ci] + kc + 32);         \
        }                                                                      \
    }

    #pragma unroll 1
    for (int k = 0; k < 64; k += 2) {
        HALF(eA, vA, k);
        HALF(eB, vB, k + 1);
    }
#undef HALF

    // ---- softmax denominators: reduce lane sums over the 4 lq groups ----
    float s0 = sacc0;
    s0 += __shfl_xor(s0, 16);
    s0 += __shfl_xor(s0, 32);
    float s1 = sacc1;
    s1 += __shfl_xor(s1, 16);
    s1 += __shfl_xor(s1, 32);

    // ---- epilogue ----
    const float g = gamma[0];
    const float scale0 = g / s0, scale1 = g / s1;
    #pragma unroll
    for (int mi = 0; mi < 2; ++mi) {
        const int m = m0 + mh + mi * 16 + lrow;
        const float sc = mi ? scale1 : scale0;
        #pragma unroll
        for (int ci = 0; ci < 4; ++ci) {
            #pragma unroll
            for (int rr = 0; rr < 4; ++rr) {
                const int c = c0 + ci * 16 + lq * 4 + rr;
                const size_t off = ((size_t)(b * Cc + c)) * Nn + m;
                Out[off] = sc * acc[ci][mi][rr] + 2.0f * X[off];
            }
        }
    }
}

extern "C" void kernel_launch(void* const* d_in, const int* in_sizes, int n_in,
                              void* d_out, int out_size, void* d_ws, size_t ws_size,
                              hipStream_t stream) {
    const float* energy  = (const float*)d_in[0];  // [4,4096,4096]
    const float* x       = (const float*)d_in[1];  // [4,256,64,64]
    const float* value_w = (const float*)d_in[2];  // [256,256]
    const float* value_b = (const float*)d_in[3];  // [256]
    const float* gamma   = (const float*)d_in[4];  // [1]
    float* out = (float*)d_out;
    unsigned short* Vws = (unsigned short*)d_ws;   // 4*256*4096 bf16 = 8 MB

    value_gemm<<<1024, 256, 0, stream>>>(x, value_w, value_b, Vws);
    attn_gemm<<<256, 512, 0, stream>>>(Vws, energy, x, gamma, out);
}

// Round 8
// 480.483 us; speedup vs baseline: 1.7391x; 1.7391x over previous
//
#include <hip/hip_runtime.h>

#define Nn 4096
#define Cc 256
#define NN2 ((size_t)Nn * Nn)

typedef __attribute__((ext_vector_type(8))) short bf16x8;
typedef __attribute__((ext_vector_type(4))) float f32x4;

// Barrier draining ONLY LDS ops; global register loads stay in flight.
#define LDSBAR() do { \
    asm volatile("s_waitcnt lgkmcnt(0)" ::: "memory"); \
    __builtin_amdgcn_s_barrier(); \
} while (0)

// one-instruction packed f32x2 -> bf16x2 (RNE), gfx950
__device__ __forceinline__ unsigned cvtpk(float lo, float hi) {
    unsigned r;
    asm("v_cvt_pk_bf16_f32 %0, %1, %2" : "=v"(r) : "v"(lo), "v"(hi));
    return r;
}

__device__ __forceinline__ bf16x8 cvt8(const float4 a, const float4 b) {
    union { unsigned u[4]; bf16x8 v; } o;
    o.u[0] = cvtpk(a.x, a.y); o.u[1] = cvtpk(a.z, a.w);
    o.u[2] = cvtpk(b.x, b.y); o.u[3] = cvtpk(b.z, b.w);
    return o.v;
}

// exp 8 floats, accumulate into sacc, pack bf16x8, 16B LDS store
__device__ __forceinline__ void expstore8(const float4 a, const float4 b,
                                          unsigned short* dst, float& sacc) {
    float4 ea, eb;
    ea.x = __expf(a.x); ea.y = __expf(a.y); ea.z = __expf(a.z); ea.w = __expf(a.w);
    eb.x = __expf(b.x); eb.y = __expf(b.y); eb.z = __expf(b.z); eb.w = __expf(b.w);
    sacc += ((ea.x + ea.y) + (ea.z + ea.w)) + ((eb.x + eb.y) + (eb.z + eb.w));
    *(bf16x8*)dst = cvt8(ea, eb);
}

// ---------------------------------------------------------------------------
// FUSED single kernel, ZERO workspace (kills the 1 GiB per-iteration poison
// and value_gemm entirely). Reassociation: out = W@(X@P^T)/S + g*bias + 2x.
// Grid 256 (b=(blk&7)>>1 pins batch to an XCD pair; 64-row m-tiles), 512 thr.
// Main loop = round-4 proven skeleton: Bexp bf16 LDS double-buffer (verified
// swizzle), register E prefetch at distance 2, ONE LDS-only barrier/step.
// A-operand = X f32 -> bf16 via v_cvt_pk (wave owns q-slice 32, m all 64).
// Epilogue: Y (acc) -> Ylds bf16 [m][q] swizzled -> tiny W@Y GEMM -> out.
// Working set ~116 VGPR: fits the empirical 128-VGPR ceiling BY DESIGN.
// ---------------------------------------------------------------------------
__global__ __launch_bounds__(512) void fused_attn(
    const float* __restrict__ E, const float* __restrict__ X,
    const float* __restrict__ W, const float* __restrict__ bias,
    const float* __restrict__ gamma, float* __restrict__ Out)
{
    __shared__ unsigned short Bexp[2][64 * 64];   // exp(E) [m][k] bf16, swizzled, 16 KB
    __shared__ unsigned short Ylds[64 * 256];     // Y [m][q] bf16, swizzled, 32 KB
    __shared__ float sum_lds[64];

    const int t = threadIdx.x;
    const int wave = t >> 6, lane = t & 63;
    const int lrow = lane & 15, lq = lane >> 4;
    const int blk = blockIdx.x;
    const int b  = (blk & 7) >> 1;                      // batch -> XCD pair
    const int m0 = (((blk >> 3) << 1) | (blk & 1)) << 6; // 64-row m-tile
    const int q0 = wave << 5;                            // q-slice (main) / c-slice (epi)

    // E staging: thread owns row erow (0..63), 8 floats at col eg*8
    const int erow = t >> 3, eg = t & 7;
    const float* ep = E + (size_t)b * NN2 + (size_t)(m0 + erow) * Nn + eg * 8;
    unsigned short* const bst0 = &Bexp[0][erow * 64 + ((eg ^ (erow & 7)) << 3)];
    unsigned short* const bst1 = &Bexp[1][erow * 64 + ((eg ^ (erow & 7)) << 3)];

    // X A-frag rows: q = q0 + ci*16 + lrow, k-cols lq*8 (+ kstep*64 + kk*32)
    const float* xp0 = X + (size_t)b * Cc * Nn + (size_t)(q0 + lrow) * Nn + lq * 8;
    const float* xp1 = xp0 + (size_t)16 * Nn;

    f32x4 acc[2][4] = {};   // Y accumulator [ci][mi]
    float sacc = 0.f;

    float4 e0a, e0b, e1a, e1b;   // E prefetch pairs (distance 2)
    bf16x8 xA[4], xB[4];         // X frags [kk*2+ci], ping-pong

    // ---- prologue ----
    e0a = *(const float4*)(ep);       e0b = *(const float4*)(ep + 4);    // E(0)
    e1a = *(const float4*)(ep + 64);  e1b = *(const float4*)(ep + 68);   // E(1)
    #pragma unroll
    for (int kk = 0; kk < 2; ++kk) {
        xA[kk * 2 + 0] = cvt8(*(const float4*)(xp0 + kk * 32),
                              *(const float4*)(xp0 + kk * 32 + 4));
        xA[kk * 2 + 1] = cvt8(*(const float4*)(xp1 + kk * 32),
                              *(const float4*)(xp1 + kk * 32 + 4));
    }
    expstore8(e0a, e0b, bst0, sacc);                                     // Bexp[0]=expE(0)
    e0a = *(const float4*)(ep + 128); e0b = *(const float4*)(ep + 132);  // E(2)
    LDSBAR();

    // step K: consume Bexp[K&1] x Xc; load X(K+1)->Xn; stage expE(K+1) from
    // (Ea,Eb); refill (Ea,Eb) <- E(K+3). One barrier.
#define STEP(K, Xc, Xn, Ea, Eb, LAST)                                          \
    {                                                                          \
        if (!(LAST)) {                                                         \
            const int kx = ((K) + 1) << 6;                                     \
            _Pragma("unroll")                                                  \
            for (int kk = 0; kk < 2; ++kk) {                                   \
                Xn[kk * 2 + 0] = cvt8(*(const float4*)(xp0 + kx + kk * 32),    \
                                      *(const float4*)(xp0 + kx + kk * 32 + 4));\
                Xn[kk * 2 + 1] = cvt8(*(const float4*)(xp1 + kx + kk * 32),    \
                                      *(const float4*)(xp1 + kx + kk * 32 + 4));\
            }                                                                  \
            expstore8(Ea, Eb, ((K) & 1) ? bst0 : bst1, sacc);                  \
            const int ke = (((K) + 3) & 63) << 6;                              \
            Ea = *(const float4*)(ep + ke);                                    \
            Eb = *(const float4*)(ep + ke + 4);                                \
        }                                                                      \
        __builtin_amdgcn_s_setprio(1);                                         \
        _Pragma("unroll")                                                      \
        for (int mi = 0; mi < 4; ++mi) {                                       \
            const int rm = mi * 16 + lrow;                                     \
            const bf16x8 f0 = *(const bf16x8*)                                 \
                &Bexp[(K) & 1][rm * 64 + ((lq ^ (rm & 7)) << 3)];              \
            const bf16x8 f1 = *(const bf16x8*)                                 \
                &Bexp[(K) & 1][rm * 64 + (((4 + lq) ^ (rm & 7)) << 3)];        \
            acc[0][mi] = __builtin_amdgcn_mfma_f32_16x16x32_bf16(              \
                Xc[0], f0, acc[0][mi], 0, 0, 0);                               \
            acc[1][mi] = __builtin_amdgcn_mfma_f32_16x16x32_bf16(              \
                Xc[1], f0, acc[1][mi], 0, 0, 0);                               \
            acc[0][mi] = __builtin_amdgcn_mfma_f32_16x16x32_bf16(              \
                Xc[2], f1, acc[0][mi], 0, 0, 0);                               \
            acc[1][mi] = __builtin_amdgcn_mfma_f32_16x16x32_bf16(              \
                Xc[3], f1, acc[1][mi], 0, 0, 0);                               \
        }                                                                      \
        __builtin_amdgcn_s_setprio(0);                                         \
        LDSBAR();                                                              \
    }

    #pragma unroll 1
    for (int k = 0; k < 62; k += 2) {
        STEP(k,     xA, xB, e1a, e1b, 0);
        STEP(k + 1, xB, xA, e0a, e0b, 0);
    }
    STEP(62, xA, xB, e1a, e1b, 0);
    STEP(63, xB, xA, e0a, e0b, 1);
#undef STEP

    // ---- softmax denominators: 8 owner-threads per m-row (same wave) ----
    {
        float s = sacc;
        s += __shfl_xor(s, 1);
        s += __shfl_xor(s, 2);
        s += __shfl_xor(s, 4);
        if (eg == 0) sum_lds[erow] = s;
    }

    // ---- Y -> Ylds bf16 [m][q], 8-col-block XOR swizzle ----
    #pragma unroll
    for (int ci = 0; ci < 2; ++ci) {
        #pragma unroll
        for (int mi = 0; mi < 4; ++mi) {
            const int m = mi * 16 + lrow;
            const int q = q0 + ci * 16 + lq * 4;       // + rr (0..3)
            const unsigned u0 = cvtpk(acc[ci][mi][0], acc[ci][mi][1]);
            const unsigned u1 = cvtpk(acc[ci][mi][2], acc[ci][mi][3]);
            unsigned short* dst =
                &Ylds[m * 256 + ((((q >> 3) ^ (m & 7)) << 3) | (q & 7))];
            *(unsigned long long*)dst =
                (unsigned long long)u0 | ((unsigned long long)u1 << 32);
        }
    }
    __syncthreads();

    // ---- epilogue GEMM: out[c 32, m 64] per wave = W[c,q] @ Ylds[q,m] ----
    f32x4 a2[2][4] = {};
    const float* wp0 = W + (size_t)(q0 + lrow) * Cc + lq * 8;
    const float* wp1 = wp0 + (size_t)16 * Cc;
    #pragma unroll
    for (int kq = 0; kq < 8; ++kq) {
        const bf16x8 wf0 = cvt8(*(const float4*)(wp0 + kq * 32),
                                *(const float4*)(wp0 + kq * 32 + 4));
        const bf16x8 wf1 = cvt8(*(const float4*)(wp1 + kq * 32),
                                *(const float4*)(wp1 + kq * 32 + 4));
        #pragma unroll
        for (int mi = 0; mi < 4; ++mi) {
            const int m = mi * 16 + lrow;
            const bf16x8 yf = *(const bf16x8*)
                &Ylds[m * 256 + ((((kq * 4 + lq) ^ (m & 7)) << 3))];
            a2[0][mi] = __builtin_amdgcn_mfma_f32_16x16x32_bf16(
                wf0, yf, a2[0][mi], 0, 0, 0);
            a2[1][mi] = __builtin_amdgcn_mfma_f32_16x16x32_bf16(
                wf1, yf, a2[1][mi], 0, 0, 0);
        }
    }

    // ---- final: out = (g/S)*a2 + g*bias + 2*x ----
    const float g = gamma[0];
    #pragma unroll
    for (int mi = 0; mi < 4; ++mi) {
        const int mloc = mi * 16 + lrow;
        const float scale = g / sum_lds[mloc];
        const int m = m0 + mloc;
        #pragma unroll
        for (int ci = 0; ci < 2; ++ci) {
            #pragma unroll
            for (int rr = 0; rr < 4; ++rr) {
                const int c = q0 + ci * 16 + lq * 4 + rr;
                const size_t off = ((size_t)(b * Cc + c)) * Nn + m;
                Out[off] = scale * a2[ci][mi][rr] + g * bias[c] + 2.0f * X[off];
            }
        }
    }
}

extern "C" void kernel_launch(void* const* d_in, const int* in_sizes, int n_in,
                              void* d_out, int out_size, void* d_ws, size_t ws_size,
                              hipStream_t stream) {
    const float* energy  = (const float*)d_in[0];  // [4,4096,4096]
    const float* x       = (const float*)d_in[1];  // [4,256,64,64]
    const float* value_w = (const float*)d_in[2];  // [256,256]
    const float* value_b = (const float*)d_in[3];  // [256]
    const float* gamma   = (const float*)d_in[4];  // [1]
    float* out = (float*)d_out;
    (void)d_ws; (void)ws_size;                     // workspace intentionally unused

    fused_attn<<<256, 512, 0, stream>>>(energy, x, value_w, value_b, gamma, out);
}